// Round 2
// baseline (413.766 us; speedup 1.0000x reference)
//
#include <hip/hip_runtime.h>
#include <cmath>

#define BB 16
#define CC 64
#define PP 16384   // H*W = 128*128

typedef float f32x4 __attribute__((ext_vector_type(4)));
typedef short bf16x8 __attribute__((ext_vector_type(8)));   // 8 bf16 = 4 VGPRs (MFMA A/B frag)
typedef int i32x4 __attribute__((ext_vector_type(4)));
typedef unsigned int u32;

// hi = trunc-to-bf16 pair packed (elem0 in low half), lo = bf16(v - hi) pair.
// v = hi + lo exact to ~2^-25 rel; 3-product MFMA covers the needed terms.
__device__ __forceinline__ void split_pair(float v0, float v1, u32& hi, u32& lo) {
    u32 u0 = __builtin_bit_cast(u32, v0);
    u32 u1 = __builtin_bit_cast(u32, v1);
    u32 h0 = u0 & 0xFFFF0000u;
    u32 h1 = u1 & 0xFFFF0000u;
    hi = (h0 >> 16) | h1;
    float l0 = v0 - __builtin_bit_cast(float, h0);
    float l1 = v1 - __builtin_bit_cast(float, h1);
    lo = (__builtin_bit_cast(u32, l0) >> 16) | (__builtin_bit_cast(u32, l1) & 0xFFFF0000u);
}

// ---------------------------------------------------------------------------
// Kernel 1: channel means. grid = 2048 blocks, TWO contiguous planes each
// (planes c and c+1 are adjacent in [b][c][p] layout -> one 128 KiB region).
// 2048 blocks x 4 waves = 32 waves/CU: whole grid resident in ONE dispatch
// round, no block turnover; 32 independent float4 loads in flight per thread.
// ---------------------------------------------------------------------------
__global__ __launch_bounds__(256) void k_means(const float* __restrict__ low,
                                               const float* __restrict__ high,
                                               const float* __restrict__ flow,
                                               const float* __restrict__ fb,
                                               float* __restrict__ cf) {
    int g0 = blockIdx.x * 2;               // plane index: b*256 + t*64 + c  (c even)
    int b = g0 >> 8, t = (g0 >> 6) & 3, c = g0 & 63;
    const float* in = (t == 0) ? low : (t == 1) ? high : (t == 2) ? flow : fb;
    const float4* p = (const float4*)(in + ((size_t)(b * CC + c)) * PP);
    int tid = threadIdx.x;

    float s0 = 0.f, s1 = 0.f;
    #pragma unroll
    for (int i = 0; i < 16; ++i) {
        float4 va = p[tid + i * 256];
        float4 vb = p[4096 + tid + i * 256];
        s0 += (va.x + va.y) + (va.z + va.w);
        s1 += (vb.x + vb.y) + (vb.z + vb.w);
    }
    #pragma unroll
    for (int off = 32; off > 0; off >>= 1) {
        s0 += __shfl_down(s0, off, 64);
        s1 += __shfl_down(s1, off, 64);
    }

    __shared__ float r[2][4];
    if ((tid & 63) == 0) { r[0][tid >> 6] = s0; r[1][tid >> 6] = s1; }
    __syncthreads();
    if (tid == 0) {
        cf[g0]     = ((r[0][0] + r[0][1]) + (r[0][2] + r[0][3])) * (1.0f / PP);
        cf[g0 + 1] = ((r[1][0] + r[1][1]) + (r[1][2] + r[1][3])) * (1.0f / PP);
    }
}

// ---------------------------------------------------------------------------
// Kernel 2: adjacency + GCN + SE heads + effective mixing matrices.
// grid = B blocks, 256 threads. Emits A pre-split to bf16 hi/lo, k-pair
// packed u32 (lo16 = bf16(A[2k2]), hi16 = bf16(A[2k2+1])), layout
// Ah/Al[b][k2][o], k2 = (t*64+c)/2, o contiguous -> k_gemm loads fragments
// as 4 dwords with ZERO split VALU.
// ---------------------------------------------------------------------------
__global__ __launch_bounds__(256) void k_small(const float* __restrict__ cf,
    const float* __restrict__ Wgcn, const float* __restrict__ bgcn,
    const float* __restrict__ W1, const float* __restrict__ b1,
    const float* __restrict__ W2, const float* __restrict__ b2,
    const float* __restrict__ W3, const float* __restrict__ b3,
    const float* __restrict__ W4, const float* __restrict__ b4,
    const float* __restrict__ Wgate,
    u32* __restrict__ Ah, u32* __restrict__ Al) {
    int b = blockIdx.x;
    int tid = threadIdx.x;
    int lane = tid & 63;
    int wid = tid >> 6;                    // wave-uniform
    __shared__ float x[4][64];
    __shared__ float nrm[4];
    __shared__ float adj[16];
    __shared__ float y[4][64];
    __shared__ float fc[256];
    __shared__ float e[4][64];

    x[wid][lane] = cf[b * 256 + tid];
    __syncthreads();

    if (tid < 4) {
        float s = 0.f;
        for (int c = 0; c < 64; ++c) s += x[tid][c] * x[tid][c];
        nrm[tid] = sqrtf(s);
    }
    __syncthreads();

    if (tid < 16) {
        int i = tid >> 2, j = tid & 3;
        float s = 0.f;
        for (int c = 0; c < 64; ++c) s += x[i][c] * x[j][c];
        adj[tid] = s / (nrm[i] * nrm[j]);
    }
    __syncthreads();

    {   // y = adj @ x
        float s = 0.f;
        #pragma unroll
        for (int j = 0; j < 4; ++j) s += adj[wid * 4 + j] * x[j][lane];
        y[wid][lane] = s;
    }
    __syncthreads();

    {   // fc = relu(y @ Wgcn + bgcn)
        float s = bgcn[lane];
        for (int c = 0; c < 64; ++c) s += y[wid][c] * Wgcn[c * 64 + lane];
        fc[wid * 64 + lane] = fmaxf(s, 0.f);
    }
    __syncthreads();

    {   // e_k = sigmoid(fc @ Wk^T + bk); wave wid handles head wid.
        const float* Wk = (wid == 0) ? W1 : (wid == 1) ? W2 : (wid == 2) ? W3 : W4;
        const float* bk = (wid == 0) ? b1 : (wid == 1) ? b2 : (wid == 2) ? b3 : b4;
        float4 fv = *(const float4*)&fc[lane * 4];
        for (int c = 0; c < 64; ++c) {
            float4 w = *(const float4*)(Wk + c * 256 + lane * 4);
            float part = (w.x * fv.x + w.y * fv.y) + (w.z * fv.z + w.w * fv.w);
            #pragma unroll
            for (int off = 32; off > 0; off >>= 1)
                part += __shfl_down(part, off, 64);
            if (lane == 0) {
                float s = part + bk[c];
                e[wid][c] = 1.f / (1.f + expf(-s));
            }
        }
    }
    __syncthreads();

    // A[t][c][o] = Wg[o,t*64+c] + e[t][c]*(sum_q Wg[o,q*64+c] - Wg[o,t*64+c])
    // then split to bf16 hi/lo, k-pair packed.
    {
        int t = wid, o = lane;
        const float* wrow = Wgate + o * 256;
        u32* Ahb = Ah + b * 8192;          // [128][64]
        u32* Alb = Al + b * 8192;
        #pragma unroll 4
        for (int c4 = 0; c4 < 64; c4 += 4) {
            float4 w0 = *(const float4*)(wrow + c4);
            float4 w1 = *(const float4*)(wrow + 64 + c4);
            float4 w2 = *(const float4*)(wrow + 128 + c4);
            float4 w3 = *(const float4*)(wrow + 192 + c4);
            float4 wt = (t == 0) ? w0 : (t == 1) ? w1 : (t == 2) ? w2 : w3;
            float4 sm = make_float4((w0.x + w1.x) + (w2.x + w3.x),
                                    (w0.y + w1.y) + (w2.y + w3.y),
                                    (w0.z + w1.z) + (w2.z + w3.z),
                                    (w0.w + w1.w) + (w2.w + w3.w));
            float a0 = wt.x + e[t][c4 + 0] * (sm.x - wt.x);
            float a1 = wt.y + e[t][c4 + 1] * (sm.y - wt.y);
            float a2 = wt.z + e[t][c4 + 2] * (sm.z - wt.z);
            float a3 = wt.w + e[t][c4 + 3] * (sm.w - wt.w);
            u32 h01, l01, h23, l23;
            split_pair(a0, a1, h01, l01);
            split_pair(a2, a3, h23, l23);
            int k2 = (t * 64 + c4) >> 1;
            Ahb[(k2 + 0) * 64 + o] = h01;
            Alb[(k2 + 0) * 64 + o] = l01;
            Ahb[(k2 + 1) * 64 + o] = h23;
            Alb[(k2 + 1) * 64 + o] = l23;
        }
    }
}

// ---------------------------------------------------------------------------
// Kernel 3 (MFMA): out[b,o,p] = sum_k A2[k,o]*X[k,p] + bgate[o],
// k = t*64+c (K=256), via mfma_f32_16x16x32_bf16 with bf16 hi/lo split
// (3 products: Ah*Xh + Ah*Xl + Al*Xh -> fp32-class accuracy).
// A arrives pre-split/packed from k_small (4 dword loads per fragment,
// no split VALU). X split on the fly. grid = B*64 blocks, 4 waves; each
// wave owns 64 pixels x all 64 outputs -> X fetched exactly once.
// ---------------------------------------------------------------------------
__global__ __launch_bounds__(256, 2) void k_gemm(const float* __restrict__ low,
    const float* __restrict__ high, const float* __restrict__ flow,
    const float* __restrict__ fb, const u32* __restrict__ Ah,
    const u32* __restrict__ Al,
    const float* __restrict__ bgate, float* __restrict__ out) {
    int blk = blockIdx.x;
    int b = blk >> 6;
    int tile = blk & 63;
    int tid = threadIdx.x;
    int lane = tid & 63;
    int wv = tid >> 6;                    // wave id: p-subrange of 64
    int l15 = lane & 15;
    int kq = (lane >> 4) << 3;            // quarter-wave k offset: 0,8,16,24

    int pbase = tile * 256 + wv * 64 + l15;        // p for p-tile 0 (col = lane&15)
    size_t xoff = (size_t)b * (CC * PP) + (size_t)kq * PP + pbase;
    const float* px[4] = {low + xoff, high + xoff, flow + xoff, fb + xoff};
    // packed A: row k2 = (t*64+h*32+kq)/2 + d, col o = ot*16 + l15
    const u32* Ahp = Ah + b * 8192 + (kq >> 1) * 64 + l15;
    const u32* Alp = Al + b * 8192 + (kq >> 1) * 64 + l15;

    f32x4 acc[4][4];                      // [o-tile][p-tile]
    #pragma unroll
    for (int i = 0; i < 4; ++i)
        #pragma unroll
        for (int j = 0; j < 4; ++j) acc[i][j] = (f32x4)(0.f);

    #pragma unroll
    for (int t = 0; t < 4; ++t) {
        const float* xp = px[t];
        #pragma unroll
        for (int h = 0; h < 2; ++h) {     // k-chunk of 32 within tensor t
            // ---- gather raw fp32 X fragments (per lane: row kq+j, col l15) --
            float xr[4][8];
            #pragma unroll
            for (int pt = 0; pt < 4; ++pt)
                #pragma unroll
                for (int j = 0; j < 8; ++j)
                    xr[pt][j] = xp[(size_t)(h * 32 + j) * PP + pt * 16];

            // ---- pre-split A fragments: 4 dword loads each, no VALU ----
            bf16x8 ah[4], al[4];
            #pragma unroll
            for (int ot = 0; ot < 4; ++ot) {
                i32x4 hv, lv;
                #pragma unroll
                for (int d = 0; d < 4; ++d) {
                    int row = t * 32 + h * 16 + d;
                    hv[d] = (int)Ahp[row * 64 + ot * 16];
                    lv[d] = (int)Alp[row * 64 + ot * 16];
                }
                ah[ot] = __builtin_bit_cast(bf16x8, hv);
                al[ot] = __builtin_bit_cast(bf16x8, lv);
            }

            // ---- split X into bf16 hi/lo fragments ----
            bf16x8 xh[4], xl[4];
            #pragma unroll
            for (int pt = 0; pt < 4; ++pt) {
                i32x4 hd, ld;
                #pragma unroll
                for (int d = 0; d < 4; ++d) {
                    u32 hi, lo;
                    split_pair(xr[pt][2 * d], xr[pt][2 * d + 1], hi, lo);
                    hd[d] = (int)hi; ld[d] = (int)lo;
                }
                xh[pt] = __builtin_bit_cast(bf16x8, hd);
                xl[pt] = __builtin_bit_cast(bf16x8, ld);
            }

            // ---- 48 MFMAs: D[o][p] += A^T-slice * X-slice (K=32) ----
            #pragma unroll
            for (int ot = 0; ot < 4; ++ot)
                #pragma unroll
                for (int pt = 0; pt < 4; ++pt) {
                    acc[ot][pt] = __builtin_amdgcn_mfma_f32_16x16x32_bf16(
                        ah[ot], xh[pt], acc[ot][pt], 0, 0, 0);
                    acc[ot][pt] = __builtin_amdgcn_mfma_f32_16x16x32_bf16(
                        ah[ot], xl[pt], acc[ot][pt], 0, 0, 0);
                    acc[ot][pt] = __builtin_amdgcn_mfma_f32_16x16x32_bf16(
                        al[ot], xh[pt], acc[ot][pt], 0, 0, 0);
                }
        }
    }

    // ---- epilogue: C/D layout col=lane&15, row=(lane>>4)*4+reg ----
    int rg = lane >> 4;
    size_t obase = (size_t)b * (CC * PP) + (size_t)pbase;
    #pragma unroll
    for (int ot = 0; ot < 4; ++ot)
        #pragma unroll
        for (int r = 0; r < 4; ++r) {
            int o = ot * 16 + rg * 4 + r;
            float bg = bgate[o];
            #pragma unroll
            for (int pt = 0; pt < 4; ++pt)
                out[obase + (size_t)o * PP + pt * 16] = acc[ot][pt][r] + bg;
        }
}

extern "C" void kernel_launch(void* const* d_in, const int* in_sizes, int n_in,
                              void* d_out, int out_size, void* d_ws, size_t ws_size,
                              hipStream_t stream) {
    const float* low  = (const float*)d_in[0];
    const float* high = (const float*)d_in[1];
    const float* flow = (const float*)d_in[2];
    const float* fb   = (const float*)d_in[3];
    const float* Wgcn = (const float*)d_in[4];
    const float* bgcn = (const float*)d_in[5];
    const float* W1   = (const float*)d_in[6];
    const float* b1   = (const float*)d_in[7];
    const float* W2   = (const float*)d_in[8];
    const float* b2   = (const float*)d_in[9];
    const float* W3   = (const float*)d_in[10];
    const float* b3   = (const float*)d_in[11];
    const float* W4   = (const float*)d_in[12];
    const float* b4   = (const float*)d_in[13];
    const float* Wgate = (const float*)d_in[14];
    const float* bgate = (const float*)d_in[15];
    float* out = (float*)d_out;

    float* cf = (float*)d_ws;                      // [16][4][64]
    u32* Ah   = (u32*)d_ws + 4096;                 // [16][128][64] packed bf16-hi pairs
    u32* Al   = (u32*)d_ws + 4096 + BB * 8192;     // [16][128][64] packed bf16-lo pairs

    k_means<<<BB * 4 * CC / 2, 256, 0, stream>>>(low, high, flow, fb, cf);
    k_small<<<BB, 256, 0, stream>>>(cf, Wgcn, bgcn, W1, b1, W2, b2, W3, b3,
                                    W4, b4, Wgate, Ah, Al);
    k_gemm<<<BB * CC, 256, 0, stream>>>(low, high, flow, fb, Ah, Al, bgate, out);
}

// Round 3
// 390.769 us; speedup vs baseline: 1.0589x; 1.0589x over previous
//
#include <hip/hip_runtime.h>
#include <cmath>

#define BB 16
#define CC 64
#define PP 16384   // H*W = 128*128

typedef float f32x4 __attribute__((ext_vector_type(4)));
typedef short bf16x8 __attribute__((ext_vector_type(8)));   // 8 bf16 = 4 VGPRs (MFMA A/B frag)
typedef int i32x4 __attribute__((ext_vector_type(4)));
typedef unsigned int u32;

// hi = trunc-to-bf16 pair packed (elem0 in low half), lo = bf16(v - hi) pair.
// v = hi + lo exact to ~2^-25 rel; 3-product MFMA covers the needed terms.
__device__ __forceinline__ void split_pair(float v0, float v1, u32& hi, u32& lo) {
    u32 u0 = __builtin_bit_cast(u32, v0);
    u32 u1 = __builtin_bit_cast(u32, v1);
    u32 h0 = u0 & 0xFFFF0000u;
    u32 h1 = u1 & 0xFFFF0000u;
    hi = (h0 >> 16) | h1;
    float l0 = v0 - __builtin_bit_cast(float, h0);
    float l1 = v1 - __builtin_bit_cast(float, h1);
    lo = (__builtin_bit_cast(u32, l0) >> 16) | (__builtin_bit_cast(u32, l1) & 0xFFFF0000u);
}

// ---------------------------------------------------------------------------
// Kernel 1: channel means. grid = B*4*C = 4096 blocks, one 64 KiB plane each.
// All 16 float4 loads issued into a register array BEFORE any use: 16 KB
// outstanding per wave (vs ~5 loads when the compiler serialized at 36 VGPR)
// -> latency-covered streaming instead of vmcnt-stall per pair.
// ---------------------------------------------------------------------------
__global__ __launch_bounds__(256) void k_means(const float* __restrict__ low,
                                               const float* __restrict__ high,
                                               const float* __restrict__ flow,
                                               const float* __restrict__ fb,
                                               float* __restrict__ cf) {
    int g = blockIdx.x;                    // plane index: b*256 + t*64 + c
    int b = g >> 8, t = (g >> 6) & 3, c = g & 63;
    const float* in = (t == 0) ? low : (t == 1) ? high : (t == 2) ? flow : fb;
    const float4* p = (const float4*)(in + ((size_t)(b * CC + c)) * PP);
    int tid = threadIdx.x;

    float4 v[16];
    #pragma unroll
    for (int i = 0; i < 16; ++i) v[i] = p[tid + i * 256];

    float s = 0.f;
    #pragma unroll
    for (int i = 0; i < 16; ++i) s += (v[i].x + v[i].y) + (v[i].z + v[i].w);

    #pragma unroll
    for (int off = 32; off > 0; off >>= 1) s += __shfl_down(s, off, 64);

    __shared__ float r[4];
    if ((tid & 63) == 0) r[tid >> 6] = s;
    __syncthreads();
    if (tid == 0)
        cf[g] = ((r[0] + r[1]) + (r[2] + r[3])) * (1.0f / PP);
}

// ---------------------------------------------------------------------------
// Kernel 2: adjacency + GCN + SE heads + effective mixing matrices.
// grid = B blocks, 256 threads. Emits A pre-split to bf16 hi/lo, k-pair
// packed u32 (lo16 = bf16(A[2k2]), hi16 = bf16(A[2k2+1])), layout
// Ah/Al[b][k2][o], k2 = (t*64+c)/2, o contiguous -> k_gemm loads fragments
// as 4 dwords with ZERO split VALU.
// ---------------------------------------------------------------------------
__global__ __launch_bounds__(256) void k_small(const float* __restrict__ cf,
    const float* __restrict__ Wgcn, const float* __restrict__ bgcn,
    const float* __restrict__ W1, const float* __restrict__ b1,
    const float* __restrict__ W2, const float* __restrict__ b2,
    const float* __restrict__ W3, const float* __restrict__ b3,
    const float* __restrict__ W4, const float* __restrict__ b4,
    const float* __restrict__ Wgate,
    u32* __restrict__ Ah, u32* __restrict__ Al) {
    int b = blockIdx.x;
    int tid = threadIdx.x;
    int lane = tid & 63;
    int wid = tid >> 6;                    // wave-uniform
    __shared__ float x[4][64];
    __shared__ float nrm[4];
    __shared__ float adj[16];
    __shared__ float y[4][64];
    __shared__ float fc[256];
    __shared__ float e[4][64];

    x[wid][lane] = cf[b * 256 + tid];
    __syncthreads();

    if (tid < 4) {
        float s = 0.f;
        for (int c = 0; c < 64; ++c) s += x[tid][c] * x[tid][c];
        nrm[tid] = sqrtf(s);
    }
    __syncthreads();

    if (tid < 16) {
        int i = tid >> 2, j = tid & 3;
        float s = 0.f;
        for (int c = 0; c < 64; ++c) s += x[i][c] * x[j][c];
        adj[tid] = s / (nrm[i] * nrm[j]);
    }
    __syncthreads();

    {   // y = adj @ x
        float s = 0.f;
        #pragma unroll
        for (int j = 0; j < 4; ++j) s += adj[wid * 4 + j] * x[j][lane];
        y[wid][lane] = s;
    }
    __syncthreads();

    {   // fc = relu(y @ Wgcn + bgcn)
        float s = bgcn[lane];
        for (int c = 0; c < 64; ++c) s += y[wid][c] * Wgcn[c * 64 + lane];
        fc[wid * 64 + lane] = fmaxf(s, 0.f);
    }
    __syncthreads();

    {   // e_k = sigmoid(fc @ Wk^T + bk); wave wid handles head wid.
        const float* Wk = (wid == 0) ? W1 : (wid == 1) ? W2 : (wid == 2) ? W3 : W4;
        const float* bk = (wid == 0) ? b1 : (wid == 1) ? b2 : (wid == 2) ? b3 : b4;
        float4 fv = *(const float4*)&fc[lane * 4];
        for (int c = 0; c < 64; ++c) {
            float4 w = *(const float4*)(Wk + c * 256 + lane * 4);
            float part = (w.x * fv.x + w.y * fv.y) + (w.z * fv.z + w.w * fv.w);
            #pragma unroll
            for (int off = 32; off > 0; off >>= 1)
                part += __shfl_down(part, off, 64);
            if (lane == 0) {
                float s = part + bk[c];
                e[wid][c] = 1.f / (1.f + expf(-s));
            }
        }
    }
    __syncthreads();

    // A[t][c][o] = Wg[o,t*64+c] + e[t][c]*(sum_q Wg[o,q*64+c] - Wg[o,t*64+c])
    // then split to bf16 hi/lo, k-pair packed.
    {
        int t = wid, o = lane;
        const float* wrow = Wgate + o * 256;
        u32* Ahb = Ah + b * 8192;          // [128][64]
        u32* Alb = Al + b * 8192;
        #pragma unroll 4
        for (int c4 = 0; c4 < 64; c4 += 4) {
            float4 w0 = *(const float4*)(wrow + c4);
            float4 w1 = *(const float4*)(wrow + 64 + c4);
            float4 w2 = *(const float4*)(wrow + 128 + c4);
            float4 w3 = *(const float4*)(wrow + 192 + c4);
            float4 wt = (t == 0) ? w0 : (t == 1) ? w1 : (t == 2) ? w2 : w3;
            float4 sm = make_float4((w0.x + w1.x) + (w2.x + w3.x),
                                    (w0.y + w1.y) + (w2.y + w3.y),
                                    (w0.z + w1.z) + (w2.z + w3.z),
                                    (w0.w + w1.w) + (w2.w + w3.w));
            float a0 = wt.x + e[t][c4 + 0] * (sm.x - wt.x);
            float a1 = wt.y + e[t][c4 + 1] * (sm.y - wt.y);
            float a2 = wt.z + e[t][c4 + 2] * (sm.z - wt.z);
            float a3 = wt.w + e[t][c4 + 3] * (sm.w - wt.w);
            u32 h01, l01, h23, l23;
            split_pair(a0, a1, h01, l01);
            split_pair(a2, a3, h23, l23);
            int k2 = (t * 64 + c4) >> 1;
            Ahb[(k2 + 0) * 64 + o] = h01;
            Alb[(k2 + 0) * 64 + o] = l01;
            Ahb[(k2 + 1) * 64 + o] = h23;
            Alb[(k2 + 1) * 64 + o] = l23;
        }
    }
}

// ---------------------------------------------------------------------------
// Kernel 3 (MFMA): out[b,o,p] = sum_k A2[k,o]*X[k,p] + bgate[o],
// k = t*64+c (K=256), via mfma_f32_16x16x32_bf16 with bf16 hi/lo split
// (3 products: Ah*Xh + Ah*Xl + Al*Xh -> fp32-class accuracy).
// A-fragments streamed per-ot with one-ahead prefetch to keep peak VGPR
// ~120 (no launch_bounds cap -> no spill). out written nontemporal (never
// re-read before reset) so it doesn't evict L3-resident X.
// ---------------------------------------------------------------------------
__global__ __launch_bounds__(256) void k_gemm(const float* __restrict__ low,
    const float* __restrict__ high, const float* __restrict__ flow,
    const float* __restrict__ fb, const u32* __restrict__ Ah,
    const u32* __restrict__ Al,
    const float* __restrict__ bgate, float* __restrict__ out) {
    int blk = blockIdx.x;
    int b = blk >> 6;
    int tile = blk & 63;
    int tid = threadIdx.x;
    int lane = tid & 63;
    int wv = tid >> 6;                    // wave id: p-subrange of 64
    int l15 = lane & 15;
    int kq = (lane >> 4) << 3;            // quarter-wave k offset: 0,8,16,24

    int pbase = tile * 256 + wv * 64 + l15;        // p for p-tile 0 (col = lane&15)
    size_t xoff = (size_t)b * (CC * PP) + (size_t)kq * PP + pbase;
    const float* px[4] = {low + xoff, high + xoff, flow + xoff, fb + xoff};
    // packed A: row k2 = (t*64+h*32+kq)/2 + d, col o = ot*16 + l15
    const u32* Ahp = Ah + b * 8192 + (kq >> 1) * 64 + l15;
    const u32* Alp = Al + b * 8192 + (kq >> 1) * 64 + l15;

    f32x4 acc[4][4];                      // [o-tile][p-tile]
    #pragma unroll
    for (int i = 0; i < 4; ++i)
        #pragma unroll
        for (int j = 0; j < 4; ++j) acc[i][j] = (f32x4)(0.f);

    #pragma unroll
    for (int t = 0; t < 4; ++t) {
        const float* xp = px[t];
        #pragma unroll
        for (int h = 0; h < 2; ++h) {     // k-chunk of 32 within tensor t
            // ---- gather raw fp32 X fragments (per lane: row kq+j, col l15) --
            float xr[4][8];
            #pragma unroll
            for (int pt = 0; pt < 4; ++pt)
                #pragma unroll
                for (int j = 0; j < 8; ++j)
                    xr[pt][j] = xp[(size_t)(h * 32 + j) * PP + pt * 16];

            // ---- A fragment for ot=0 (issued before X split for overlap) ---
            i32x4 hc, lc;
            #pragma unroll
            for (int d = 0; d < 4; ++d) {
                int row = t * 32 + h * 16 + d;
                hc[d] = (int)Ahp[row * 64];
                lc[d] = (int)Alp[row * 64];
            }

            // ---- split X into bf16 hi/lo fragments (xr dies here) ----
            bf16x8 xh[4], xl[4];
            #pragma unroll
            for (int pt = 0; pt < 4; ++pt) {
                i32x4 hd, ld;
                #pragma unroll
                for (int d = 0; d < 4; ++d) {
                    u32 hi, lo;
                    split_pair(xr[pt][2 * d], xr[pt][2 * d + 1], hi, lo);
                    hd[d] = (int)hi; ld[d] = (int)lo;
                }
                xh[pt] = __builtin_bit_cast(bf16x8, hd);
                xl[pt] = __builtin_bit_cast(bf16x8, ld);
            }

            // ---- per-ot: 12 MFMAs with one-ahead A prefetch ----
            #pragma unroll
            for (int ot = 0; ot < 4; ++ot) {
                bf16x8 ah = __builtin_bit_cast(bf16x8, hc);
                bf16x8 al = __builtin_bit_cast(bf16x8, lc);
                if (ot < 3) {
                    #pragma unroll
                    for (int d = 0; d < 4; ++d) {
                        int row = t * 32 + h * 16 + d;
                        hc[d] = (int)Ahp[row * 64 + (ot + 1) * 16];
                        lc[d] = (int)Alp[row * 64 + (ot + 1) * 16];
                    }
                }
                #pragma unroll
                for (int pt = 0; pt < 4; ++pt) {
                    acc[ot][pt] = __builtin_amdgcn_mfma_f32_16x16x32_bf16(
                        ah, xh[pt], acc[ot][pt], 0, 0, 0);
                    acc[ot][pt] = __builtin_amdgcn_mfma_f32_16x16x32_bf16(
                        ah, xl[pt], acc[ot][pt], 0, 0, 0);
                    acc[ot][pt] = __builtin_amdgcn_mfma_f32_16x16x32_bf16(
                        al, xh[pt], acc[ot][pt], 0, 0, 0);
                }
            }
        }
    }

    // ---- epilogue: C/D layout col=lane&15, row=(lane>>4)*4+reg ----
    int rg = lane >> 4;
    size_t obase = (size_t)b * (CC * PP) + (size_t)pbase;
    #pragma unroll
    for (int ot = 0; ot < 4; ++ot)
        #pragma unroll
        for (int r = 0; r < 4; ++r) {
            int o = ot * 16 + rg * 4 + r;
            float bg = bgate[o];
            #pragma unroll
            for (int pt = 0; pt < 4; ++pt)
                __builtin_nontemporal_store(acc[ot][pt][r] + bg,
                    out + obase + (size_t)o * PP + pt * 16);
        }
}

extern "C" void kernel_launch(void* const* d_in, const int* in_sizes, int n_in,
                              void* d_out, int out_size, void* d_ws, size_t ws_size,
                              hipStream_t stream) {
    const float* low  = (const float*)d_in[0];
    const float* high = (const float*)d_in[1];
    const float* flow = (const float*)d_in[2];
    const float* fb   = (const float*)d_in[3];
    const float* Wgcn = (const float*)d_in[4];
    const float* bgcn = (const float*)d_in[5];
    const float* W1   = (const float*)d_in[6];
    const float* b1   = (const float*)d_in[7];
    const float* W2   = (const float*)d_in[8];
    const float* b2   = (const float*)d_in[9];
    const float* W3   = (const float*)d_in[10];
    const float* b3   = (const float*)d_in[11];
    const float* W4   = (const float*)d_in[12];
    const float* b4   = (const float*)d_in[13];
    const float* Wgate = (const float*)d_in[14];
    const float* bgate = (const float*)d_in[15];
    float* out = (float*)d_out;

    float* cf = (float*)d_ws;                      // [16][4][64]
    u32* Ah   = (u32*)d_ws + 4096;                 // [16][128][64] packed bf16-hi pairs
    u32* Al   = (u32*)d_ws + 4096 + BB * 8192;     // [16][128][64] packed bf16-lo pairs

    k_means<<<BB * 4 * CC, 256, 0, stream>>>(low, high, flow, fb, cf);
    k_small<<<BB, 256, 0, stream>>>(cf, Wgcn, bgcn, W1, b1, W2, b2, W3, b3,
                                    W4, b4, Wgate, Ah, Al);
    k_gemm<<<BB * CC, 256, 0, stream>>>(low, high, flow, fb, Ah, Al, bgate, out);
}